// Round 4
// baseline (104.855 us; speedup 1.0000x reference)
//
#include <hip/hip_runtime.h>
#include <stdint.h>

// Problem constants (reference: B=8, N=16384, F=128, P=28)
#define BDIM   8
#define NDIM   16384
#define FDIM   128
#define PDIM   28
#define MPTS   (BDIM * NDIM)     // 131072 points
#define SLICE  4096              // f16 per kk slab in global: 128 f x 32 q
#define QSL    1024              // f16 per kk quarter-slab: 32 f x 32 q
#define TPTS   256               // points per M-tile
#define TILES  4                 // M-tiles per block
#define CPTS   (TPTS * TILES)    // 1024 points per block

typedef _Float16 half8  __attribute__((ext_vector_type(8)));
typedef _Float16 half2v __attribute__((ext_vector_type(2)));
typedef float    floatx4 __attribute__((ext_vector_type(4)));

// ---------------------------------------------------------------------------
// Prep: IF [F][P][P] fp32 -> IFt_sw [28][128][4][8] f16.
// Slot s of row f holds ORIGINAL q-slot (s ^ ((f>>1)&3)) — XOR bank-swizzle
// baked into global so the main kernel's global_load_lds DMA writes LDS
// linearly (swizzle both sides or neither). q >= 28 zero-padded.
// ---------------------------------------------------------------------------
__global__ __launch_bounds__(256) void prep_ift(const float* __restrict__ IF,
                                                _Float16* __restrict__ IFt) {
    int idx = blockIdx.x * 256 + threadIdx.x;     // 0 .. 28*4096-1
    int kk  = idx >> 12;                          // p index
    int rem = idx & 4095;
    int f   = rem >> 5;
    int s   = (rem >> 3) & 3;
    int j   = idx & 7;
    int q   = ((s ^ ((f >> 1) & 3)) << 3) + j;    // original q
    float v = (q < PDIM) ? IF[f * (PDIM * PDIM) + kk * PDIM + q] : 0.0f;
    IFt[idx] = (_Float16)v;
}

// ---------------------------------------------------------------------------
// async global->LDS DMA, 16B per lane; LDS dest is wave-uniform base + lane*16
// ---------------------------------------------------------------------------
__device__ __forceinline__ void gload16(const _Float16* g, _Float16* l) {
    __builtin_amdgcn_global_load_lds(
        (const __attribute__((address_space(1))) void*)g,
        (__attribute__((address_space(3))) void*)l, 16, 0, 0);
}

// ---------------------------------------------------------------------------
// Main: C[m,f] = sum_k W[m,k] * IFt[k,f],  W[m, p*32+q] = k0[m,p]*k1[m,q]
//
// Each block owns a 32-feature QUARTER of B (57.3 KB), resident in LDS for
// the whole kernel; 1024 points in 4 M-tiles of 256. 8 waves all stacked in
// m (wave tile 32 pts x 32 f), mfma_f32_16x16x32_f16, acc[2][2].
//  - k1 A-fragments computed IN REGISTERS (16 expf/lane/tile) — no k1 LDS.
//  - k0t double-buffered: fill tile t+1 overlaps K-loop of tile t.
//  - Mid-kernel barriers are raw lgkmcnt(0)+s_barrier (NO vmcnt drain), so
//    epilogue stores of tile t stream out under tile t+1's compute. The only
//    vmcnt(0) barrier is the first one (drains B DMA; no stores exist yet).
//  - LDS 71.7 KB -> 2 blocks/CU; grid 512 = full residency, single round.
// ---------------------------------------------------------------------------
__global__ __launch_bounds__(512, 4) void feats_kernel(
    const float* __restrict__ x,       // [MPTS][2]
    const float* __restrict__ sigma,   // [1] log lengthscale
    const _Float16* __restrict__ IFt,  // [28][128][4][8] f16, pre-swizzled
    float* __restrict__ out)           // [MPTS][FDIM]
{
    __shared__ __align__(16) _Float16 bs [PDIM * QSL];        // 57344 B
    __shared__ __align__(16) _Float16 k0t[2][PDIM * TPTS];    // 2 x 14336 B

    const int tid   = threadIdx.x;
    const int lane  = tid & 63;
    const int wave  = tid >> 6;          // 0..7, all in m
    const int ln15  = lane & 15;
    const int quad  = lane >> 4;
    const int chunk = blockIdx.x >> 2;   // 1024-point chunk id (0..127)
    const int q4    = blockIdx.x & 3;    // feature quarter

    // ---- stage the B quarter ONCE: 28 slabs x 2KB = 3584 x 16B chunks ----
    {
        const _Float16* g = IFt + q4 * QSL;
        #pragma unroll
        for (int it = 0; it < 7; it++) {
            const int i   = it * 512 + tid;
            const int kk  = i >> 7;            // wave-uniform (64 | 128)
            const int off = (i & 127) * 8;     // consecutive per lane
            gload16(g + kk * SLICE + off, &bs[kk * QSL + off]);
        }
    }

    const float ls    = __expf(sigma[0]);
    const float inv   = 0.5f / (ls * ls);
    const float gstep = 0.998f / 27.0f;

    // ---- k0t fill: 512 threads x (256 points x 28 p): each does 14 expf ----
    // point m -> m' = (m&~31) + (m&15)*2 + ((m>>4)&1)  (b32 pairs mt=0,1)
    const int ptl = tid & 255;
    const int ph  = tid >> 8;                  // p-half: 0 -> p<14, 1 -> p>=14
    const int m_  = (ptl & ~31) + (ptl & 15) * 2 + ((ptl >> 4) & 1);

#define FILL_K0(TT, BUF)                                                      \
    do {                                                                      \
        const float x0 = x[2 * (chunk * CPTS + (TT) * TPTS + ptl)];           \
        _Pragma("unroll")                                                     \
        for (int pp = 0; pp < 14; pp++) {                                     \
            const int p = ph * 14 + pp;                                       \
            const float d = (0.001f + p * gstep) - x0;                        \
            k0t[BUF][p * TPTS + m_] = (_Float16)__expf(-inv * d * d);         \
        }                                                                     \
    } while (0)

    FILL_K0(0, 0);
    __syncthreads();   // vmcnt(0): B resident; lgkm: k0t[0] ready. No stores yet.

    // ---- K-invariant B fragment offsets ----
    // B[k = quad*8+j][f = q4*32+fl] at swizzled slot (quad ^ ((fl>>1)&3))
    // (q4*32 contributes 0 to bits 1..2 of f>>1, so fl-only swz is exact.)
    int bfo[2];
    #pragma unroll
    for (int nt = 0; nt < 2; nt++) {
        const int fl = nt * 16 + ln15;         // 0..31
        bfo[nt] = fl * 32 + ((quad ^ ((fl >> 1) & 3)) << 3);
    }
    const int k0o = wave * 32 + ln15 * 2;      // f16 idx; b32 covers mt=0,1

    #pragma unroll 1
    for (int t = 0; t < TILES; t++) {
        // fill NEXT tile's k0 into the other buffer (overlaps this K-loop)
        if (t + 1 < TILES) FILL_K0(t + 1, (t + 1) & 1);

        // ---- k1 A-fragments in registers: 16 expf per lane ----
        // A layout (16x16x32): A[m = lane&15][k = quad*8 + j], k local = q.
        half8 k1f[2];
        #pragma unroll
        for (int mt = 0; mt < 2; mt++) {
            const int pt = chunk * CPTS + t * TPTS + wave * 32 + mt * 16 + ln15;
            const float x1 = x[2 * pt + 1];
            #pragma unroll
            for (int j = 0; j < 8; j++) {
                const float d = (0.001f + (quad * 8 + j) * gstep) - x1;
                k1f[mt][j] = (_Float16)__expf(-inv * d * d);
                // q>=28 lanes: finite garbage x B=0 (zero-padded) -> 0. Safe.
            }
        }

        floatx4 acc[2][2];
        #pragma unroll
        for (int mt = 0; mt < 2; mt++)
            #pragma unroll
            for (int nt = 0; nt < 2; nt++)
                acc[mt][nt] = (floatx4){0.0f, 0.0f, 0.0f, 0.0f};

        // ---- K-loop: barrier-free, pure LDS-read + MFMA ----
        const _Float16* k0b = &k0t[t & 1][0];
        #pragma unroll 7
        for (int kk = 0; kk < PDIM; kk++) {
            half8 bf[2];
            #pragma unroll
            for (int nt = 0; nt < 2; nt++)
                bf[nt] = *(const half8*)&bs[kk * QSL + bfo[nt]];
            const half2v k0v = *(const half2v*)&k0b[kk * TPTS + k0o];
            #pragma unroll
            for (int mt = 0; mt < 2; mt++) {
                const half8 af = k1f[mt] * k0v[mt];     // v_pk_mul_f16 x4
                #pragma unroll
                for (int nt = 0; nt < 2; nt++)
                    acc[mt][nt] = __builtin_amdgcn_mfma_f32_16x16x32_f16(
                        af, bf[nt], acc[mt][nt], 0, 0, 0);
            }
        }

        // ---- epilogue: fire-and-forget nontemporal stores (never drained
        //      mid-kernel; they stream under the next tile's compute) ----
        #pragma unroll
        for (int mt = 0; mt < 2; mt++) {
            const int row0 = chunk * CPTS + t * TPTS + wave * 32 + mt * 16 + quad * 4;
            #pragma unroll
            for (int nt = 0; nt < 2; nt++) {
                const int col = q4 * 32 + nt * 16 + ln15;
                float* op = out + (size_t)row0 * FDIM + col;
                #pragma unroll
                for (int r = 0; r < 4; r++)
                    __builtin_nontemporal_store(acc[mt][nt][r], op + (size_t)r * FDIM);
            }
        }

        if (t + 1 < TILES) {
            // raw barrier: drain LDS ops only (fill t+1 writes + K-loop reads),
            // NOT vmcnt — stores stay in flight. sched_barrier pins ordering
            // (rule #18: compiler may hoist past inline-asm waitcnt).
            asm volatile("s_waitcnt lgkmcnt(0)" ::: "memory");
            __builtin_amdgcn_s_barrier();
            __builtin_amdgcn_sched_barrier(0);
        }
    }
#undef FILL_K0
}

// ---------------------------------------------------------------------------
extern "C" void kernel_launch(void* const* d_in, const int* in_sizes, int n_in,
                              void* d_out, int out_size, void* d_ws, size_t ws_size,
                              hipStream_t stream) {
    const float* x     = (const float*)d_in[0];   // [8,16384,2]
    const float* sigma = (const float*)d_in[1];   // [1]
    const float* IF    = (const float*)d_in[2];   // [128,28,28]
    float* out = (float*)d_out;                   // [8,16384,128] fp32

    // d_ws: IFt_sw f16 [28][128][4][8] = 229376 bytes
    _Float16* IFt = (_Float16*)d_ws;

    prep_ift<<<(PDIM * SLICE) / 256, 256, 0, stream>>>(IF, IFt);     // 448 blocks
    // 128 chunks of 1024 points x 4 feature quarters = 512 blocks, 2/CU,
    // full residency in a single scheduling round (zero tail).
    feats_kernel<<<(MPTS / CPTS) * 4, 512, 0, stream>>>(x, sigma, IFt, out);
}